// Round 9
// baseline (366.152 us; speedup 1.0000x reference)
//
#include <hip/hip_runtime.h>
#include <hip/hip_bf16.h>
#include <math.h>

#define DIM 64
#define HID 128
#define NRANGE 8

typedef __attribute__((ext_vector_type(8))) short bf16x8;
typedef __attribute__((ext_vector_type(4))) float f32x4;

__device__ __forceinline__ float bf2f(unsigned short us) {
    return __uint_as_float(((unsigned)us) << 16);
}
__device__ __forceinline__ unsigned short f2bf(float f) {
    unsigned u = __float_as_uint(f);
    unsigned r = u + 0x7FFFu + ((u >> 16) & 1u);   // round-to-nearest-even
    return (unsigned short)(r >> 16);
}

// ---- zero the degree counters ----------------------------------------------
__global__ __launch_bounds__(1024) void zero_cnt(int* __restrict__ cnt, int N) {
    int i = blockIdx.x * 1024 + threadIdx.x;
    if (i < N) cnt[i] = 0;
}

// ---- histogram of dst (nontemporal read: stream, don't pollute L2) ----------
__global__ void hist_kernel(const int* __restrict__ dst, int* __restrict__ cnt, int nedges) {
    int i = blockIdx.x * blockDim.x + threadIdx.x;
    int n = gridDim.x * blockDim.x;
    for (int e = i; e < nedges; e += n) {
        int d = __builtin_nontemporal_load(&dst[e]);
        atomicAdd(&cnt[d], 1);
    }
}

// ---- scan phase 1: per-block exclusive scan of cnt; dinv; cnt=0 -------------
__global__ __launch_bounds__(1024) void scan1(int* __restrict__ cnt,
                                              int* __restrict__ rowptr,
                                              int* __restrict__ bsum,
                                              float* __restrict__ dinv,
                                              int N) {
    __shared__ int wsums[16];
    int tid = threadIdx.x, lane = tid & 63, wid = tid >> 6;
    int i = blockIdx.x * 1024 + tid;
    int v = (i < N) ? cnt[i] : 0;
    int x = v;
    #pragma unroll
    for (int off = 1; off < 64; off <<= 1) {
        int y = __shfl_up(x, off, 64);
        if (lane >= off) x += y;
    }
    if (lane == 63) wsums[wid] = x;
    __syncthreads();
    if (wid == 0) {
        int t = (lane < 16) ? wsums[lane] : 0;
        #pragma unroll
        for (int off = 1; off < 16; off <<= 1) {
            int y = __shfl_up(t, off, 64);
            if (lane >= off) t += y;
        }
        if (lane < 16) wsums[lane] = t;
    }
    __syncthreads();
    int woff = wid ? wsums[wid - 1] : 0;
    int excl = woff + x - v;
    if (i < N) {
        rowptr[i] = excl;
        dinv[i] = rsqrtf((float)(1 + v));   // +1 self loop; deg >= 1 always
        cnt[i] = 0;                          // reset as placement cursor
    }
    if (tid == 0) bsum[blockIdx.x] = wsums[15];
}

// ---- scan phase 2: single-block exclusive scan of block sums (NB <= 1024) ---
__global__ __launch_bounds__(1024) void scan2(const int* __restrict__ bsum,
                                              int* __restrict__ boff,
                                              int NB) {
    __shared__ int wsums[16];
    int tid = threadIdx.x, lane = tid & 63, wid = tid >> 6;
    int v = (tid < NB) ? bsum[tid] : 0;
    int x = v;
    #pragma unroll
    for (int off = 1; off < 64; off <<= 1) {
        int y = __shfl_up(x, off, 64);
        if (lane >= off) x += y;
    }
    if (lane == 63) wsums[wid] = x;
    __syncthreads();
    if (wid == 0) {
        int t = (lane < 16) ? wsums[lane] : 0;
        #pragma unroll
        for (int off = 1; off < 16; off <<= 1) {
            int y = __shfl_up(t, off, 64);
            if (lane >= off) t += y;
        }
        if (lane < 16) wsums[lane] = t;
    }
    __syncthreads();
    int woff = wid ? wsums[wid - 1] : 0;
    if (tid < NB) boff[tid] = woff + x - v;
    if (tid == 0) boff[NB] = wsums[15];   // grand total
}

// ---- scan phase 3: add block offsets; finalize rowptr[N] --------------------
__global__ __launch_bounds__(1024) void scan3(int* __restrict__ rowptr,
                                              const int* __restrict__ boff,
                                              int N, int NB) {
    int i = blockIdx.x * 1024 + threadIdx.x;
    if (i < N) rowptr[i] += boff[blockIdx.x];
    if (i == 0) rowptr[N] = boff[NB];
}

// ---- node init: xv = bf16(clip_max_norm(x) * dinv) (dinv[s] folded in) ------
__global__ __launch_bounds__(256) void node_init(const float* __restrict__ emb,
                                                 const float* __restrict__ dinv,
                                                 unsigned short* __restrict__ xv,
                                                 int n_nodes) {
    int lane = threadIdx.x & 63;
    int wid = (blockIdx.x * 256 + threadIdx.x) >> 6;
    if (wid >= n_nodes) return;
    float v = emb[(size_t)wid * DIM + lane];
    float s = v * v;
    #pragma unroll
    for (int off = 32; off; off >>= 1) s += __shfl_xor(s, off);
    float sc = fminf(1.0f, 1.0f / (sqrtf(s) + 1e-7f));
    xv[(size_t)wid * DIM + lane] = f2bf(v * sc * dinv[wid]);
}

// ---- placement, dst-range partitioned; NT reads keep L2 for the write window
__global__ __launch_bounds__(256) void place_kernel(const int* __restrict__ src,
                                                    const int* __restrict__ dst,
                                                    const int* __restrict__ rowptr,
                                                    int* __restrict__ cnt,
                                                    int* __restrict__ srcs,
                                                    int nedges, int rsize) {
    int r = blockIdx.x & (NRANGE - 1);
    int lo = r * rsize, hi = lo + rsize;
    int tid = (blockIdx.x >> 3) * 256 + threadIdx.x;
    int stride = (gridDim.x >> 3) * 256;
    for (int e = tid; e < nedges; e += stride) {
        int d = __builtin_nontemporal_load(&dst[e]);
        if (d < lo || d >= hi) continue;
        int s = __builtin_nontemporal_load(&src[e]);
        int slot = rowptr[d] + atomicAdd(&cnt[d], 1);
        srcs[slot] = s;
    }
}

// ---- gather1: ax[d] = bf16( dinv[d] * (xv[d] + sum_e xv[src_e]) ) -----------
// paired edges: lanes 0-31 = edge p (dims as bf16x2), lanes 32-63 = edge p+1.
__global__ __launch_bounds__(256) void gather_ax(const int* __restrict__ rowptr,
                                                 const int* __restrict__ srcs,
                                                 const float* __restrict__ dinv,
                                                 const unsigned* __restrict__ xv32,
                                                 unsigned* __restrict__ ax32,
                                                 int n_nodes) {
    int lane = threadIdx.x & 63;
    int node = (blockIdx.x * 256 + threadIdx.x) >> 6;
    if (node >= n_nodes) return;
    int half = lane >> 5;
    int li = lane & 31;
    int beg = rowptr[node], end = rowptr[node + 1];
    float a0 = 0.f, a1 = 0.f;
    if (half == 0) {   // self term
        unsigned v = xv32[(size_t)node * 32 + li];
        a0 += bf2f((unsigned short)v);
        a1 += bf2f((unsigned short)(v >> 16));
    }
    int p = beg + half;
    for (; p + 2 < end; p += 4) {   // 2 edges per half in flight
        int s0 = srcs[p], s1 = srcs[p + 2];
        unsigned v0 = xv32[(size_t)s0 * 32 + li];
        unsigned v1 = xv32[(size_t)s1 * 32 + li];
        a0 += bf2f((unsigned short)v0) + bf2f((unsigned short)v1);
        a1 += bf2f((unsigned short)(v0 >> 16)) + bf2f((unsigned short)(v1 >> 16));
    }
    for (; p < end; p += 2) {
        int s = srcs[p];
        unsigned v = xv32[(size_t)s * 32 + li];
        a0 += bf2f((unsigned short)v);
        a1 += bf2f((unsigned short)(v >> 16));
    }
    a0 += __shfl_xor(a0, 32);
    a1 += __shfl_xor(a1, 32);
    if (half == 0) {
        float dn = dinv[node];
        ax32[(size_t)node * 32 + li] =
            (unsigned)f2bf(a0 * dn) | ((unsigned)f2bf(a1 * dn) << 16);
    }
}

// ---- MFMA fused MLP: hv = (relu(ax @ W1 + b1) @ W2) * dinv ------------------
__global__ __launch_bounds__(256) void mfma_mlp(const unsigned short* __restrict__ ax,
                                                const float* __restrict__ W1,
                                                const float* __restrict__ b1,
                                                const float* __restrict__ W2,
                                                const float* __restrict__ dinv,
                                                float* __restrict__ hv,
                                                int n_nodes, int ntiles) {
    __shared__ unsigned short w1t[128][72];   // W1T[n][k] = W1[k][n]
    __shared__ unsigned short w2t[64][136];   // W2T[n][k] = W2[k][n]
    __shared__ unsigned short axl[32][72];
    __shared__ unsigned short hL[32][136];
    __shared__ float b1l[128];
    int tid = threadIdx.x;
    for (int idx = tid; idx < DIM * HID; idx += 256) {
        int k = idx >> 7, n = idx & 127;
        w1t[n][k] = f2bf(W1[idx]);
    }
    for (int idx = tid; idx < HID * DIM; idx += 256) {
        int k = idx >> 6, n = idx & 63;
        w2t[n][k] = f2bf(W2[idx]);
    }
    if (tid < 128) b1l[tid] = b1[tid];
    int lane = tid & 63;
    int w = tid >> 6;
    int l15 = lane & 15;
    int lq = lane >> 4;
    __syncthreads();

    for (int t = blockIdx.x; t < ntiles; t += gridDim.x) {
        int row0 = t * 32;
        {
            int r = tid >> 3, c8 = (tid & 7) * 8;
            int n = row0 + r;
            uint4 v = {0u, 0u, 0u, 0u};
            if (n < n_nodes) v = *(const uint4*)&ax[(size_t)n * DIM + c8];
            *(uint4*)&axl[r][c8] = v;
        }
        __syncthreads();
        f32x4 acc00 = {}, acc01 = {}, acc10 = {}, acc11 = {};
        #pragma unroll
        for (int kk = 0; kk < 2; ++kk) {
            int kb = kk * 32 + lq * 8;
            bf16x8 a0 = *(const bf16x8*)&axl[l15][kb];
            bf16x8 a1 = *(const bf16x8*)&axl[16 + l15][kb];
            bf16x8 b0 = *(const bf16x8*)&w1t[w * 32 + l15][kb];
            bf16x8 b1v = *(const bf16x8*)&w1t[w * 32 + 16 + l15][kb];
            acc00 = __builtin_amdgcn_mfma_f32_16x16x32_bf16(a0, b0, acc00, 0, 0, 0);
            acc01 = __builtin_amdgcn_mfma_f32_16x16x32_bf16(a0, b1v, acc01, 0, 0, 0);
            acc10 = __builtin_amdgcn_mfma_f32_16x16x32_bf16(a1, b0, acc10, 0, 0, 0);
            acc11 = __builtin_amdgcn_mfma_f32_16x16x32_bf16(a1, b1v, acc11, 0, 0, 0);
        }
        {
            int c0 = w * 32 + l15, c1 = w * 32 + 16 + l15;
            float bb0 = b1l[c0], bb1 = b1l[c1];
            #pragma unroll
            for (int r = 0; r < 4; ++r) {
                hL[lq * 4 + r][c0]      = f2bf(fmaxf(acc00[r] + bb0, 0.f));
                hL[lq * 4 + r][c1]      = f2bf(fmaxf(acc01[r] + bb1, 0.f));
                hL[16 + lq * 4 + r][c0] = f2bf(fmaxf(acc10[r] + bb0, 0.f));
                hL[16 + lq * 4 + r][c1] = f2bf(fmaxf(acc11[r] + bb1, 0.f));
            }
        }
        __syncthreads();
        f32x4 o0 = {}, o1 = {};
        #pragma unroll
        for (int kk = 0; kk < 4; ++kk) {
            int kb = kk * 32 + lq * 8;
            bf16x8 h0 = *(const bf16x8*)&hL[l15][kb];
            bf16x8 h1 = *(const bf16x8*)&hL[16 + l15][kb];
            bf16x8 bw = *(const bf16x8*)&w2t[w * 16 + l15][kb];
            o0 = __builtin_amdgcn_mfma_f32_16x16x32_bf16(h0, bw, o0, 0, 0, 0);
            o1 = __builtin_amdgcn_mfma_f32_16x16x32_bf16(h1, bw, o1, 0, 0, 0);
        }
        #pragma unroll
        for (int r = 0; r < 4; ++r) {
            int row = row0 + lq * 4 + r;
            if (row < n_nodes)
                hv[(size_t)row * DIM + w * 16 + l15] = o0[r] * dinv[row];
            int row2 = row + 16;
            if (row2 < n_nodes)
                hv[(size_t)row2 * DIM + w * 16 + l15] = o1[r] * dinv[row2];
        }
        __syncthreads();
    }
}

// ---- fused layer-2 gather + final, batch-wide only --------------------------
__global__ __launch_bounds__(256) void item_final(const int* __restrict__ rowptr,
                                                  const int* __restrict__ srcs,
                                                  const float* __restrict__ dinv,
                                                  const float* __restrict__ hv,
                                                  const float* __restrict__ b2,
                                                  const float* __restrict__ user_emb,
                                                  const int* __restrict__ u,
                                                  const int* __restrict__ iid,
                                                  float* __restrict__ out,
                                                  int batch) {
    int lane = threadIdx.x & 63;
    int b = (blockIdx.x * 256 + threadIdx.x) >> 6;
    if (b >= batch) return;
    int ii = iid[b], uu = u[b];
    float uv = user_emb[(size_t)uu * DIM + lane];
    float s = uv * uv;
    #pragma unroll
    for (int off = 32; off; off >>= 1) s += __shfl_xor(s, off);
    float sc = fminf(1.0f, 1.0f / (sqrtf(s) + 1e-7f));
    float acc = hv[(size_t)ii * DIM + lane];
    int beg = rowptr[ii], end = rowptr[ii + 1];
    int p = beg;
    for (; p + 1 < end; p += 2) {
        int s0 = srcs[p], s1 = srcs[p + 1];
        acc += hv[(size_t)s0 * DIM + lane] + hv[(size_t)s1 * DIM + lane];
    }
    if (p < end) acc += hv[(size_t)srcs[p] * DIM + lane];
    float item = dinv[ii] * acc + b2[lane];
    float dot = uv * sc * item;
    #pragma unroll
    for (int off = 32; off; off >>= 1) dot += __shfl_xor(dot, off);
    if (lane == 0) out[b] = 1.0f / (1.0f + expf(-dot));
}

extern "C" void kernel_launch(void* const* d_in, const int* in_sizes, int n_in,
                              void* d_out, int out_size, void* d_ws, size_t ws_size,
                              hipStream_t stream) {
    const float* entity = (const float*)d_in[0];
    const float* user   = (const float*)d_in[1];
    const float* W1     = (const float*)d_in[2];
    const float* b1     = (const float*)d_in[3];
    const float* W2     = (const float*)d_in[4];
    const float* b2     = (const float*)d_in[5];
    const int*   u      = (const int*)d_in[6];
    const int*   iid    = (const int*)d_in[7];
    const int*   eidx   = (const int*)d_in[8];

    int N = in_sizes[0] / DIM;      // 100000
    int B = in_sizes[6];            // 8192
    int E = in_sizes[8] / 2;        // 1600000
    const int* src = eidx;
    const int* dst = eidx + E;
    int NB = (N + 1023) / 1024;     // 98 (<= 1024)
    int ntiles = (N + 31) / 32;     // 3125
    int rsize = (N + NRANGE - 1) / NRANGE;   // 12500

    // workspace layout, 16B-aligned segments
    char* p = (char*)d_ws;
    auto alloc = [&](size_t bytes) { char* r = p; p += (bytes + 15) & ~(size_t)15; return r; };
    int*   cnt    = (int*)alloc((size_t)N * 4);
    int*   rowptr = (int*)alloc((size_t)(N + 1) * 4);
    int*   bsum   = (int*)alloc((size_t)NB * 4);
    int*   boff   = (int*)alloc((size_t)(NB + 1) * 4);
    float* dinv   = (float*)alloc((size_t)N * 4);
    int*   srcs   = (int*)alloc((size_t)E * 4);
    unsigned short* xv = (unsigned short*)alloc((size_t)N * DIM * 2);
    unsigned short* ax = (unsigned short*)alloc((size_t)N * DIM * 2);
    float* hv     = (float*)alloc((size_t)N * DIM * 4);
    float* outF   = (float*)d_out;

    zero_cnt<<<NB, 1024, 0, stream>>>(cnt, N);
    hist_kernel<<<1024, 256, 0, stream>>>(dst, cnt, E);
    scan1<<<NB, 1024, 0, stream>>>(cnt, rowptr, bsum, dinv, N);
    scan2<<<1, 1024, 0, stream>>>(bsum, boff, NB);
    scan3<<<NB, 1024, 0, stream>>>(rowptr, boff, N, NB);
    node_init<<<(N * 64 + 255) / 256, 256, 0, stream>>>(entity, dinv, xv, N);
    place_kernel<<<2048, 256, 0, stream>>>(src, dst, rowptr, cnt, srcs, E, rsize);
    gather_ax<<<(N * 64 + 255) / 256, 256, 0, stream>>>(rowptr, srcs, dinv,
                                                        (const unsigned*)xv, (unsigned*)ax, N);
    mfma_mlp<<<512, 256, 0, stream>>>(ax, W1, b1, W2, dinv, hv, N, ntiles);
    item_final<<<(B * 64 + 255) / 256, 256, 0, stream>>>(rowptr, srcs, dinv, hv, b2, user, u, iid, outF, B);
}